// Round 11
// baseline (125.533 us; speedup 1.0000x reference)
//
#include <hip/hip_runtime.h>
#include <hip/hip_bf16.h>
#include <math.h>

typedef __bf16 bf16x8 __attribute__((ext_vector_type(8)));
typedef float f32x4 __attribute__((ext_vector_type(4)));

// QSCALE * log2(e): Q (and the bias tables derived from Q) live in the exp2
// domain, so softmax needs only exp2f.
#define QSCALE_L2E (0.08838834764831845f * 1.4426950408889634f)

static __device__ __forceinline__ unsigned short bits_bf16(float v) {
  __hip_bfloat16 h = __float2bfloat16(v);
  return *reinterpret_cast<unsigned short*>(&h);
}

// async global->LDS DMA, 16B per lane; LDS dest = wave-uniform base + lane*16
static __device__ __forceinline__ void gload16(const void* g, void* l) {
  __builtin_amdgcn_global_load_lds(
      (const __attribute__((address_space(1))) void*)g,
      (__attribute__((address_space(3))) void*)l, 16, 0, 0);
}

// ---------------- kernel 1: convert weights + rel tables to bf16 ----------------
__global__ __launch_bounds__(256) void k_convw(const float* __restrict__ wqk,
                                               const float* __restrict__ wv,
                                               const float* __restrict__ relw,
                                               const float* __restrict__ relh,
                                               __hip_bfloat16* __restrict__ wall,
                                               __hip_bfloat16* __restrict__ relsb) {
  int i = blockIdx.x * 256 + threadIdx.x;
  if (i < 1536 * 512) {
    float v = (i < 1024 * 512) ? wqk[i] : wv[i - 1024 * 512];
    wall[i] = __float2bfloat16(v);
  } else {
    int j = i - 1536 * 512;  // 0..16383 : [2][64][128], row 63 of each table = 0
    int t = j >> 13, m = (j >> 7) & 63, d = j & 127;
    float v = (m < 63) ? (t ? relh[m * 128 + d] : relw[m * 128 + d]) : 0.f;
    relsb[j] = __float2bfloat16(v);
  }
}

// ---------------- kernel 2: transpose + convert featuremap -> [B][L][C] bf16 ----------------
__global__ __launch_bounds__(256) void k_tfm(const float* __restrict__ fm,
                                             __hip_bfloat16* __restrict__ fmt) {
  __shared__ float t[64][65];
  int lt = blockIdx.x, ct = blockIdx.y, b = blockIdx.z;
  int tid = threadIdx.x;
  const float* src = fm + ((size_t)b * 512 + ct * 64) * 1024 + lt * 64;
#pragma unroll
  for (int i = 0; i < 16; ++i) {
    int idx = i * 256 + tid;
    int r = idx >> 6, cl = idx & 63;
    t[r][cl] = src[(size_t)r * 1024 + cl];
  }
  __syncthreads();
  __hip_bfloat16* dst = fmt + ((size_t)b * 1024 + lt * 64) * 512 + ct * 64;
#pragma unroll
  for (int i = 0; i < 16; ++i) {
    int idx = i * 256 + tid;
    int r = idx >> 6, cc = idx & 63;
    dst[(size_t)r * 512 + cc] = __float2bfloat16(t[cc][r]);
  }
}

// ---------------- kernel 3: QKV projection GEMM (m97 structure) ----------------
__global__ __launch_bounds__(256) void k_gemm(const __hip_bfloat16* __restrict__ fmt,
                                              const __hip_bfloat16* __restrict__ wall,
                                              __hip_bfloat16* __restrict__ Qb,
                                              __hip_bfloat16* __restrict__ Kb,
                                              __hip_bfloat16* __restrict__ Vt) {
  __shared__ char smem[32768];
  char* As = smem;
  char* Bs = smem + 16384;
  int bm = blockIdx.x, bn = blockIdx.y, b = blockIdx.z;
  int tid = threadIdx.x;
  int lane = tid & 63, wave = tid >> 6;
  int wr = wave >> 1, wc = wave & 1;
  int g = lane >> 4, ln = lane & 15;
  const char* Ag = (const char*)(fmt + ((size_t)b * 1024 + bm * 128) * 512);
  const char* Bg = (const char*)(wall + (size_t)bn * 128 * 512);

  int j3 = lane >> 3, j7 = lane & 7;
  int segsrc = ((j7 ^ j3) << 4);  // pre-swizzled source seg (row&7 == j3)

  f32x4 acc[4][4] = {};
  for (int kb = 0; kb < 8; ++kb) {
#pragma unroll
    for (int i = 0; i < 4; ++i) {
      int R = (wave * 4 + i) * 8;  // 8 rows per 1KB DMA
      size_t go = (size_t)(R + j3) * 1024 + (size_t)kb * 128 + segsrc;
      gload16(Ag + go, As + R * 128);
      gload16(Bg + go, Bs + R * 128);
    }
    __syncthreads();
#pragma unroll
    for (int ks = 0; ks < 2; ++ks) {
      int kcol = ks * 64 + (g << 4);
      bf16x8 af[4], bfr[4];
#pragma unroll
      for (int m = 0; m < 4; ++m) {
        int row = wr * 64 + m * 16 + ln;
        af[m] = *(const bf16x8*)(As + row * 128 + (kcol ^ ((ln & 7) << 4)));
      }
#pragma unroll
      for (int n = 0; n < 4; ++n) {
        int row = wc * 64 + n * 16 + ln;
        bfr[n] = *(const bf16x8*)(Bs + row * 128 + (kcol ^ ((ln & 7) << 4)));
      }
#pragma unroll
      for (int m = 0; m < 4; ++m)
#pragma unroll
        for (int n = 0; n < 4; ++n)
          acc[m][n] = __builtin_amdgcn_mfma_f32_16x16x32_bf16(af[m], bfr[n], acc[m][n], 0, 0, 0);
    }
    __syncthreads();
  }

  // ---- epilogue: restage C tile in LDS, then coalesced row stores ----
  int otype = bn >> 2;  // 0=q, 1=k, 2=v
  int head = bn & 3;
  if (otype != 2) {
    float sc = (otype == 0) ? QSCALE_L2E : 1.0f;
#pragma unroll
    for (int m = 0; m < 4; ++m)
#pragma unroll
      for (int n = 0; n < 4; ++n) {
        int d = wc * 64 + n * 16 + ln;
#pragma unroll
        for (int r = 0; r < 4; ++r) {
          int l = wr * 64 + m * 16 + g * 4 + r;
          *(__hip_bfloat16*)(smem + l * 256 + ((d * 2) ^ ((l & 7) << 4))) =
              __float2bfloat16(acc[m][n][r] * sc);
        }
      }
    __syncthreads();
    __hip_bfloat16* dstb =
        (otype == 0 ? Qb : Kb) + (((size_t)(b * 4 + head) * 1024) + bm * 128) * 128;
#pragma unroll
    for (int i = 0; i < 8; ++i) {
      int idx = i * 256 + tid;
      int row = idx >> 4, c16 = idx & 15;
      uint4 v = *(const uint4*)(smem + row * 256 + ((c16 * 16) ^ ((row & 7) << 4)));
      *(uint4*)(dstb + (size_t)row * 128 + c16 * 8) = v;
    }
  } else {
#pragma unroll
    for (int m = 0; m < 4; ++m)
#pragma unroll
      for (int n = 0; n < 4; ++n) {
        int d = wc * 64 + n * 16 + ln;
        int lbase = wr * 64 + m * 16 + g * 4;
        ushort4 pk;
        pk.x = bits_bf16(acc[m][n][0]);
        pk.y = bits_bf16(acc[m][n][1]);
        pk.z = bits_bf16(acc[m][n][2]);
        pk.w = bits_bf16(acc[m][n][3]);
        *(ushort4*)(smem + d * 256 + ((lbase * 2) ^ ((d & 7) << 4))) = pk;
      }
    __syncthreads();
    __hip_bfloat16* dstb = Vt + ((size_t)(b * 4 + head) * 128) * 1024 + bm * 128;
#pragma unroll
    for (int i = 0; i < 8; ++i) {
      int idx = i * 256 + tid;
      int row = idx >> 4, c16 = idx & 15;
      uint4 v = *(const uint4*)(smem + row * 256 + ((c16 * 16) ^ ((row & 7) << 4)));
      *(uint4*)(dstb + (size_t)row * 1024 + c16 * 8) = v;
    }
  }
}

// ---------------- kernel 4: bias tables via MFMA ----------------
// Tables inherit the log2e factor from Qb automatically.
__global__ __launch_bounds__(256) void k_bias(const __hip_bfloat16* __restrict__ Qb,
                                              const __hip_bfloat16* __restrict__ relsb,
                                              float* __restrict__ QRW,
                                              float* __restrict__ QRH) {
  __shared__ char sh[32768];  // [2][64][128] bf16, swizzled
  int bx = blockIdx.x, bh = blockIdx.y;
  int tid = threadIdx.x, lane = tid & 63, wave = tid >> 6;
  int g = lane >> 4, ln = lane & 15;
#pragma unroll
  for (int i = 0; i < 8; ++i) {
    int chunk = i * 256 + tid;
    int row = chunk >> 4, c16 = chunk & 15;
    *(uint4*)(sh + row * 256 + ((c16 * 16) ^ ((row & 7) << 4))) =
        *(const uint4*)(relsb + (size_t)row * 128 + c16 * 8);
  }
  __syncthreads();
  size_t bhL = (size_t)bh * 1024;
  int l0 = bx * 128 + wave * 32;
  const __hip_bfloat16* Qg = Qb + (bhL + l0) * 128;
  bf16x8 a[2][4];
#pragma unroll
  for (int lf = 0; lf < 2; ++lf)
#pragma unroll
    for (int ks = 0; ks < 4; ++ks)
      a[lf][ks] = *(const bf16x8*)(Qg + (size_t)(lf * 16 + ln) * 128 + ks * 32 + g * 8);
#pragma unroll
  for (int t = 0; t < 2; ++t) {
    float* dst = (t == 0 ? QRW : QRH) + (bhL + l0) * 64;
#pragma unroll
    for (int n = 0; n < 4; ++n) {
      f32x4 acc2[2] = {};
#pragma unroll
      for (int ks = 0; ks < 4; ++ks) {
        int mrow = n * 16 + ln;
        bf16x8 bf = *(const bf16x8*)(sh + t * 16384 + mrow * 256 +
                                     ((ks * 64 + g * 16) ^ ((mrow & 7) << 4)));
#pragma unroll
        for (int lf = 0; lf < 2; ++lf)
          acc2[lf] = __builtin_amdgcn_mfma_f32_16x16x32_bf16(a[lf][ks], bf, acc2[lf], 0, 0, 0);
      }
#pragma unroll
      for (int lf = 0; lf < 2; ++lf)
#pragma unroll
        for (int r = 0; r < 4; ++r)
          dst[(size_t)(lf * 16 + g * 4 + r) * 64 + n * 16 + ln] = acc2[lf][r];
    }
  }
}

// ---------------- kernel 5: fused attention (8 waves, 256 q/block, K/V dbuf 2-phase) ----------------
// Swapped QK^T + 2 q-sets/wave (r9-verified core). Double-buffered K/V staged
// via global_load_lds with the stage for tile t+1 issued BEFORE computing tile
// t; single barrier per kt hides HBM latency under compute (T3-minimal).
__global__ __launch_bounds__(512, 2) void k_attn(const __hip_bfloat16* __restrict__ Qb,
                                                 const __hip_bfloat16* __restrict__ Kb,
                                                 const __hip_bfloat16* __restrict__ Vt,
                                                 const float* __restrict__ QRW,
                                                 const float* __restrict__ QRH,
                                                 float* __restrict__ out) {
  extern __shared__ char smem[];
  float* hb_s = (float*)smem;                 // [256][40] f32 = 40960 B
  char* kbuf = smem + 40960;                  // K dbuf [2][64][256B] = 32768 B
  char* vbuf = smem + 40960 + 32768;          // V dbuf [2][128][128B] = 32768 B
  char* pt = smem + 40960 + 65536;            // P [8 waves][32][128B] = 32768 B
                                              // total 139264 B

  int bh = blockIdx.x, qt = blockIdx.y;  // same-bh blocks differ by 64 in linear id -> same XCD
  int b = bh >> 2, h = bh & 3;
  int tid = threadIdx.x, lane = tid & 63, wave = tid >> 6;  // wave 0..7
  int g = lane >> 4, ln = lane & 15;
  int q0 = qt * 256;
  size_t bhL = (size_t)bh * 1024;

  // stage hb rows: aligned 36-float window of QRH per q-row (start = (31-rx)&~3)
#pragma unroll
  for (int i = 0; i < 5; ++i) {
    int c = i * 512 + tid;  // 256 rows x 9 chunks = 2304
    if (c < 2304) {
      int row = c / 9, j = c % 9;
      int s0 = (31 - ((q0 + row) >> 5)) & ~3;
      *(uint4*)(hb_s + row * 40 + j * 4) =
          *(const uint4*)(QRH + (bhL + q0 + row) * 64 + s0 + j * 4);
    }
  }

  // per-q-set constants + direct global->reg loads (one-time)
  bf16x8 qa[2][4];
  float wb[2][2][4];
  int qloc[2], hbase[2];
#pragma unroll
  for (int u = 0; u < 2; ++u) {
    qloc[u] = wave * 32 + u * 16 + ln;
    int qg = q0 + qloc[u];
    int cx = qg & 31, rx = qg >> 5;
    hbase[u] = (31 - rx) & 3;
    const __hip_bfloat16* qrow = Qb + (bhL + qg) * 128;
#pragma unroll
    for (int ks = 0; ks < 4; ++ks)
      qa[u][ks] = *(const bf16x8*)(qrow + ks * 32 + g * 8);
    const float* wrow = QRW + (bhL + qg) * 64 + (31 - cx) + g * 4;
#pragma unroll
    for (int half = 0; half < 2; ++half)
#pragma unroll
      for (int r = 0; r < 4; ++r) wb[u][half][r] = wrow[half * 16 + r];
  }

  const char* Kg0 = (const char*)(Kb + bhL * 128);
  const char* Vg0 = (const char*)(Vt + (size_t)bh * 128 * 1024);
  int j3 = lane >> 3, j7 = lane & 7;
  int segv = ((j7 ^ j3) << 4);

  // stage K/V tile kt2 into buffer bsel (2 gload16 each per wave)
  auto STAGE = [&](int bsel, int kt2) {
    const char* Kg = Kg0 + (size_t)kt2 * 64 * 256;
    char* kvb = kbuf + bsel * 16384;
#pragma unroll
    for (int i = 0; i < 2; ++i) {
      int R = (wave * 2 + i) * 4;  // chunk parity = i
      int seg = ((lane & 15) ^ ((i & 1) * 4 + (lane >> 4))) << 4;
      gload16(Kg + (size_t)(R + (lane >> 4)) * 256 + seg, kvb + R * 256);
    }
    const char* Vg = Vg0 + (size_t)kt2 * 128;
    char* vtb = vbuf + bsel * 16384;
#pragma unroll
    for (int i = 0; i < 2; ++i) {
      int R = (wave * 2 + i) * 8;
      gload16(Vg + (size_t)(R + j3) * 2048 + segv, vtb + R * 128);
    }
  };

  f32x4 acc[2][8] = {};
  float mrow[2] = {-1e30f, -1e30f}, lrow[2] = {0.f, 0.f};
  char* pw = pt + wave * 4096;

  STAGE(0, 0);
  __syncthreads();  // drains prologue stage + hb_s writes

  for (int kt = 0; kt < 16; ++kt) {
    int cur = kt & 1;
    if (kt < 15) STAGE(cur ^ 1, kt + 1);  // issue next tile early; drained at barrier below
    char* kvb = kbuf + cur * 16384;
    char* vtb = vbuf + cur * 16384;

    // S^T = K Q^T (log2 domain): s[u][n][r] = S[key=n*16+g*4+r][q=qloc[u]]
    f32x4 s[2][4] = {};
    __builtin_amdgcn_s_setprio(1);
#pragma unroll
    for (int ks = 0; ks < 4; ++ks) {
      int kcol = ks * 64 + (g << 4);
#pragma unroll
      for (int n = 0; n < 4; ++n) {
        int krow = n * 16 + ln;
        bf16x8 kf = *(const bf16x8*)(kvb + krow * 256 + (kcol ^ ((krow & 7) << 4)));
        s[0][n] = __builtin_amdgcn_mfma_f32_16x16x32_bf16(kf, qa[0][ks], s[0][n], 0, 0, 0);
        s[1][n] = __builtin_amdgcn_mfma_f32_16x16x32_bf16(kf, qa[1][ks], s[1][n], 0, 0, 0);
      }
    }
    __builtin_amdgcn_s_setprio(0);
    // bias + online softmax + P write, per q-set
#pragma unroll
    for (int u = 0; u < 2; ++u) {
      float hb0 = hb_s[qloc[u] * 40 + hbase[u] + kt * 2];
      float hb1 = hb_s[qloc[u] * 40 + hbase[u] + kt * 2 + 1];
#pragma unroll
      for (int n = 0; n < 4; ++n) {
        float hb = (n >> 1) ? hb1 : hb0;
#pragma unroll
        for (int r = 0; r < 4; ++r) s[u][n][r] += wb[u][n & 1][r] + hb;
      }
      float mt = s[u][0][0];
#pragma unroll
      for (int n = 0; n < 4; ++n)
#pragma unroll
        for (int r = 0; r < 4; ++r) mt = fmaxf(mt, s[u][n][r]);
      mt = fmaxf(mt, __shfl_xor(mt, 16, 64));
      mt = fmaxf(mt, __shfl_xor(mt, 32, 64));
      float mn = fmaxf(mrow[u], mt);
      float alpha = exp2f(mrow[u] - mn);
      mrow[u] = mn;
      float rs = 0.f;
#pragma unroll
      for (int n = 0; n < 4; ++n)
#pragma unroll
        for (int r = 0; r < 4; ++r) {
          s[u][n][r] = exp2f(s[u][n][r] - mn);
          rs += s[u][n][r];
        }
      rs += __shfl_xor(rs, 16, 64);
      rs += __shfl_xor(rs, 32, 64);
      lrow[u] = lrow[u] * alpha + rs;
#pragma unroll
      for (int mf = 0; mf < 8; ++mf) acc[u][mf] *= alpha;
#pragma unroll
      for (int n = 0; n < 4; ++n) {
        ushort4 pk;
        pk.x = bits_bf16(s[u][n][0]);
        pk.y = bits_bf16(s[u][n][1]);
        pk.z = bits_bf16(s[u][n][2]);
        pk.w = bits_bf16(s[u][n][3]);
        *(ushort4*)(pw + (u * 16 + ln) * 128 + ((n * 32 + g * 8) ^ ((ln & 7) << 4))) = pk;
      }
    }
    // PV (transposed): acc[u][d][q] += V_t . P^T ; av shared across both q-sets
    __builtin_amdgcn_s_setprio(1);
#pragma unroll
    for (int ks2 = 0; ks2 < 2; ++ks2) {
      int kcb = ks2 * 64 + (g << 4);
      bf16x8 pb0 = *(const bf16x8*)(pw + ln * 128 + (kcb ^ ((ln & 7) << 4)));
      bf16x8 pb1 = *(const bf16x8*)(pw + (16 + ln) * 128 + (kcb ^ ((ln & 7) << 4)));
#pragma unroll
      for (int mf = 0; mf < 8; ++mf) {
        int vrow = mf * 16 + ln;
        bf16x8 av = *(const bf16x8*)(vtb + vrow * 128 + (kcb ^ ((vrow & 7) << 4)));
        acc[0][mf] = __builtin_amdgcn_mfma_f32_16x16x32_bf16(av, pb0, acc[0][mf], 0, 0, 0);
        acc[1][mf] = __builtin_amdgcn_mfma_f32_16x16x32_bf16(av, pb1, acc[1][mf], 0, 0, 0);
      }
    }
    __builtin_amdgcn_s_setprio(0);
    __syncthreads();  // drains next-tile stage; releases cur buffer for overwrite
  }
  // normalize + store (l and acc columns are in-lane per q-set)
#pragma unroll
  for (int u = 0; u < 2; ++u) {
    float linv = 1.0f / lrow[u];
    int qg3 = q0 + wave * 32 + u * 16 + ln;
#pragma unroll
    for (int mf = 0; mf < 8; ++mf) {
      int dbase = mf * 16 + g * 4;
#pragma unroll
      for (int r = 0; r < 4; ++r) {
        out[((size_t)(b * 512 + h * 128 + dbase + r)) * 1024 + qg3] = acc[u][mf][r] * linv;
      }
    }
  }
}

extern "C" void kernel_launch(void* const* d_in, const int* in_sizes, int n_in,
                              void* d_out, int out_size, void* d_ws, size_t ws_size,
                              hipStream_t stream) {
  const float* fm = (const float*)d_in[0];
  const float* wqk = (const float*)d_in[1];
  const float* wv = (const float*)d_in[2];
  const float* relh = (const float*)d_in[3];
  const float* relw = (const float*)d_in[4];
  float* out = (float*)d_out;
  char* w = (char*)d_ws;

  __hip_bfloat16* fmt = (__hip_bfloat16*)w;                   // 16 MB  [B][L][C]
  __hip_bfloat16* wall = (__hip_bfloat16*)(w + 16777216);     // 1.5 MB [1536][512]
  __hip_bfloat16* Qb = (__hip_bfloat16*)(w + 18350080);       // 16 MB  [B][H][L][D] (scaled*log2e)
  __hip_bfloat16* Kb = (__hip_bfloat16*)(w + 35127296);       // 16 MB  [B][H][L][D]
  __hip_bfloat16* Vt = (__hip_bfloat16*)(w + 51904512);       // 16 MB  [B][H][D][L]
  float* QRW = (float*)(w + 68681728);                        // 16 MB  [B][H][L][64]
  float* QRH = (float*)(w + 85458944);                        // 16 MB  [B][H][L][64]
  __hip_bfloat16* relsb = (__hip_bfloat16*)(w + 102236160);   // 32 KB  [2][64][128]

  hipFuncSetAttribute((const void*)k_attn,
                      hipFuncAttributeMaxDynamicSharedMemorySize, 139264);

  k_convw<<<3136, 256, 0, stream>>>(wqk, wv, relw, relh, wall, relsb);
  k_tfm<<<dim3(16, 8, 16), 256, 0, stream>>>(fm, fmt);
  k_gemm<<<dim3(8, 12, 16), 256, 0, stream>>>(fmt, wall, Qb, Kb, Vt);
  k_bias<<<dim3(8, 64), 256, 0, stream>>>(Qb, relsb, QRW, QRH);
  k_attn<<<dim3(64, 4), 512, 139264, stream>>>(Qb, Kb, Vt, QRW, QRH, out);
}

// Round 12
// 120.865 us; speedup vs baseline: 1.0386x; 1.0386x over previous
//
#include <hip/hip_runtime.h>
#include <hip/hip_bf16.h>
#include <math.h>

typedef __bf16 bf16x8 __attribute__((ext_vector_type(8)));
typedef float f32x4 __attribute__((ext_vector_type(4)));

// QSCALE * log2(e): Q (and the bias tables derived from Q) live in the exp2
// domain, so softmax needs only exp2f.
#define QSCALE_L2E (0.08838834764831845f * 1.4426950408889634f)

static __device__ __forceinline__ unsigned short bits_bf16(float v) {
  __hip_bfloat16 h = __float2bfloat16(v);
  return *reinterpret_cast<unsigned short*>(&h);
}

// async global->LDS DMA, 16B per lane; LDS dest = wave-uniform base + lane*16
static __device__ __forceinline__ void gload16(const void* g, void* l) {
  __builtin_amdgcn_global_load_lds(
      (const __attribute__((address_space(1))) void*)g,
      (__attribute__((address_space(3))) void*)l, 16, 0, 0);
}

// ---------------- kernel 1: convert weights + rel tables to bf16 ----------------
__global__ __launch_bounds__(256) void k_convw(const float* __restrict__ wqk,
                                               const float* __restrict__ wv,
                                               const float* __restrict__ relw,
                                               const float* __restrict__ relh,
                                               __hip_bfloat16* __restrict__ wall,
                                               __hip_bfloat16* __restrict__ relsb) {
  int i = blockIdx.x * 256 + threadIdx.x;
  if (i < 1536 * 512) {
    float v = (i < 1024 * 512) ? wqk[i] : wv[i - 1024 * 512];
    wall[i] = __float2bfloat16(v);
  } else {
    int j = i - 1536 * 512;  // 0..16383 : [2][64][128], row 63 of each table = 0
    int t = j >> 13, m = (j >> 7) & 63, d = j & 127;
    float v = (m < 63) ? (t ? relh[m * 128 + d] : relw[m * 128 + d]) : 0.f;
    relsb[j] = __float2bfloat16(v);
  }
}

// ---------------- kernel 2: transpose + convert featuremap -> [B][L][C] bf16 ----------------
__global__ __launch_bounds__(256) void k_tfm(const float* __restrict__ fm,
                                             __hip_bfloat16* __restrict__ fmt) {
  __shared__ float t[64][65];
  int lt = blockIdx.x, ct = blockIdx.y, b = blockIdx.z;
  int tid = threadIdx.x;
  const float* src = fm + ((size_t)b * 512 + ct * 64) * 1024 + lt * 64;
#pragma unroll
  for (int i = 0; i < 16; ++i) {
    int idx = i * 256 + tid;
    int r = idx >> 6, cl = idx & 63;
    t[r][cl] = src[(size_t)r * 1024 + cl];
  }
  __syncthreads();
  __hip_bfloat16* dst = fmt + ((size_t)b * 1024 + lt * 64) * 512 + ct * 64;
#pragma unroll
  for (int i = 0; i < 16; ++i) {
    int idx = i * 256 + tid;
    int r = idx >> 6, cc = idx & 63;
    dst[(size_t)r * 512 + cc] = __float2bfloat16(t[cc][r]);
  }
}

// ---------------- kernel 3: QKV projection GEMM (m97 structure) ----------------
__global__ __launch_bounds__(256) void k_gemm(const __hip_bfloat16* __restrict__ fmt,
                                              const __hip_bfloat16* __restrict__ wall,
                                              __hip_bfloat16* __restrict__ Qb,
                                              __hip_bfloat16* __restrict__ Kb,
                                              __hip_bfloat16* __restrict__ Vt) {
  __shared__ char smem[32768];
  char* As = smem;
  char* Bs = smem + 16384;
  int bm = blockIdx.x, bn = blockIdx.y, b = blockIdx.z;
  int tid = threadIdx.x;
  int lane = tid & 63, wave = tid >> 6;
  int wr = wave >> 1, wc = wave & 1;
  int g = lane >> 4, ln = lane & 15;
  const char* Ag = (const char*)(fmt + ((size_t)b * 1024 + bm * 128) * 512);
  const char* Bg = (const char*)(wall + (size_t)bn * 128 * 512);

  int j3 = lane >> 3, j7 = lane & 7;
  int segsrc = ((j7 ^ j3) << 4);  // pre-swizzled source seg (row&7 == j3)

  f32x4 acc[4][4] = {};
  for (int kb = 0; kb < 8; ++kb) {
#pragma unroll
    for (int i = 0; i < 4; ++i) {
      int R = (wave * 4 + i) * 8;  // 8 rows per 1KB DMA
      size_t go = (size_t)(R + j3) * 1024 + (size_t)kb * 128 + segsrc;
      gload16(Ag + go, As + R * 128);
      gload16(Bg + go, Bs + R * 128);
    }
    __syncthreads();
#pragma unroll
    for (int ks = 0; ks < 2; ++ks) {
      int kcol = ks * 64 + (g << 4);
      bf16x8 af[4], bfr[4];
#pragma unroll
      for (int m = 0; m < 4; ++m) {
        int row = wr * 64 + m * 16 + ln;
        af[m] = *(const bf16x8*)(As + row * 128 + (kcol ^ ((ln & 7) << 4)));
      }
#pragma unroll
      for (int n = 0; n < 4; ++n) {
        int row = wc * 64 + n * 16 + ln;
        bfr[n] = *(const bf16x8*)(Bs + row * 128 + (kcol ^ ((ln & 7) << 4)));
      }
#pragma unroll
      for (int m = 0; m < 4; ++m)
#pragma unroll
        for (int n = 0; n < 4; ++n)
          acc[m][n] = __builtin_amdgcn_mfma_f32_16x16x32_bf16(af[m], bfr[n], acc[m][n], 0, 0, 0);
    }
    __syncthreads();
  }

  // ---- epilogue: restage C tile in LDS, then coalesced row stores ----
  int otype = bn >> 2;  // 0=q, 1=k, 2=v
  int head = bn & 3;
  if (otype != 2) {
    float sc = (otype == 0) ? QSCALE_L2E : 1.0f;
#pragma unroll
    for (int m = 0; m < 4; ++m)
#pragma unroll
      for (int n = 0; n < 4; ++n) {
        int d = wc * 64 + n * 16 + ln;
#pragma unroll
        for (int r = 0; r < 4; ++r) {
          int l = wr * 64 + m * 16 + g * 4 + r;
          *(__hip_bfloat16*)(smem + l * 256 + ((d * 2) ^ ((l & 7) << 4))) =
              __float2bfloat16(acc[m][n][r] * sc);
        }
      }
    __syncthreads();
    __hip_bfloat16* dstb =
        (otype == 0 ? Qb : Kb) + (((size_t)(b * 4 + head) * 1024) + bm * 128) * 128;
#pragma unroll
    for (int i = 0; i < 8; ++i) {
      int idx = i * 256 + tid;
      int row = idx >> 4, c16 = idx & 15;
      uint4 v = *(const uint4*)(smem + row * 256 + ((c16 * 16) ^ ((row & 7) << 4)));
      *(uint4*)(dstb + (size_t)row * 128 + c16 * 8) = v;
    }
  } else {
#pragma unroll
    for (int m = 0; m < 4; ++m)
#pragma unroll
      for (int n = 0; n < 4; ++n) {
        int d = wc * 64 + n * 16 + ln;
        int lbase = wr * 64 + m * 16 + g * 4;
        ushort4 pk;
        pk.x = bits_bf16(acc[m][n][0]);
        pk.y = bits_bf16(acc[m][n][1]);
        pk.z = bits_bf16(acc[m][n][2]);
        pk.w = bits_bf16(acc[m][n][3]);
        *(ushort4*)(smem + d * 256 + ((lbase * 2) ^ ((d & 7) << 4))) = pk;
      }
    __syncthreads();
    __hip_bfloat16* dstb = Vt + ((size_t)(b * 4 + head) * 128) * 1024 + bm * 128;
#pragma unroll
    for (int i = 0; i < 8; ++i) {
      int idx = i * 256 + tid;
      int row = idx >> 4, c16 = idx & 15;
      uint4 v = *(const uint4*)(smem + row * 256 + ((c16 * 16) ^ ((row & 7) << 4)));
      *(uint4*)(dstb + (size_t)row * 1024 + c16 * 8) = v;
    }
  }
}

// ---------------- kernel 4: bias tables via MFMA ----------------
// Tables inherit the log2e factor from Qb automatically.
__global__ __launch_bounds__(256) void k_bias(const __hip_bfloat16* __restrict__ Qb,
                                              const __hip_bfloat16* __restrict__ relsb,
                                              float* __restrict__ QRW,
                                              float* __restrict__ QRH) {
  __shared__ char sh[32768];  // [2][64][128] bf16, swizzled
  int bx = blockIdx.x, bh = blockIdx.y;
  int tid = threadIdx.x, lane = tid & 63, wave = tid >> 6;
  int g = lane >> 4, ln = lane & 15;
#pragma unroll
  for (int i = 0; i < 8; ++i) {
    int chunk = i * 256 + tid;
    int row = chunk >> 4, c16 = chunk & 15;
    *(uint4*)(sh + row * 256 + ((c16 * 16) ^ ((row & 7) << 4))) =
        *(const uint4*)(relsb + (size_t)row * 128 + c16 * 8);
  }
  __syncthreads();
  size_t bhL = (size_t)bh * 1024;
  int l0 = bx * 128 + wave * 32;
  const __hip_bfloat16* Qg = Qb + (bhL + l0) * 128;
  bf16x8 a[2][4];
#pragma unroll
  for (int lf = 0; lf < 2; ++lf)
#pragma unroll
    for (int ks = 0; ks < 4; ++ks)
      a[lf][ks] = *(const bf16x8*)(Qg + (size_t)(lf * 16 + ln) * 128 + ks * 32 + g * 8);
#pragma unroll
  for (int t = 0; t < 2; ++t) {
    float* dst = (t == 0 ? QRW : QRH) + (bhL + l0) * 64;
#pragma unroll
    for (int n = 0; n < 4; ++n) {
      f32x4 acc2[2] = {};
#pragma unroll
      for (int ks = 0; ks < 4; ++ks) {
        int mrow = n * 16 + ln;
        bf16x8 bf = *(const bf16x8*)(sh + t * 16384 + mrow * 256 +
                                     ((ks * 64 + g * 16) ^ ((mrow & 7) << 4)));
#pragma unroll
        for (int lf = 0; lf < 2; ++lf)
          acc2[lf] = __builtin_amdgcn_mfma_f32_16x16x32_bf16(a[lf][ks], bf, acc2[lf], 0, 0, 0);
      }
#pragma unroll
      for (int lf = 0; lf < 2; ++lf)
#pragma unroll
        for (int r = 0; r < 4; ++r)
          dst[(size_t)(lf * 16 + g * 4 + r) * 64 + n * 16 + ln] = acc2[lf][r];
    }
  }
}

// ---------------- kernel 5: fused attention (2-stage software pipeline) ----------------
// 8 waves x 32 q, swapped QK^T (r11-verified core). Per iteration: issue
// STAGE(kt+1) and QK^T(kt) [MFMA+ds_read] FIRST, then softmax+PV of tile kt-1
// [VALU] on the previous s-registers -> wave-internal overlap of matrix and
// VALU pipes; QK^T's kf reads also fill the P write->read LDS latency gap.
// K double-buffered, V triple-buffered (V consumed one iteration late).
// T13 defer-rescale (THR=8 in exp2 domain => P <= 256, bf16-safe).
__global__ __launch_bounds__(512, 2) void k_attn(const __hip_bfloat16* __restrict__ Qb,
                                                 const __hip_bfloat16* __restrict__ Kb,
                                                 const __hip_bfloat16* __restrict__ Vt,
                                                 const float* __restrict__ QRW,
                                                 const float* __restrict__ QRH,
                                                 float* __restrict__ out) {
  extern __shared__ char smem[];
  float* hb_s = (float*)smem;                 // [256][40] f32 = 40960 B
  char* kb0 = smem + 40960;                   // K buf A 16384 B
  char* kb1 = smem + 57344;                   // K buf B 16384 B
  char* vb0 = smem + 73728;                   // V buf A 16384 B
  char* vb1 = smem + 90112;                   // V buf B 16384 B
  char* vb2 = smem + 106496;                  // V buf C 16384 B
  char* pt = smem + 122880;                   // P [8 waves][32][128B] = 32768 B
                                              // total 155648 B

  int bh = blockIdx.x, qt = blockIdx.y;  // same-bh blocks: linear ids differ by 64 -> same XCD
  int b = bh >> 2, h = bh & 3;
  int tid = threadIdx.x, lane = tid & 63, wave = tid >> 6;  // wave 0..7
  int g = lane >> 4, ln = lane & 15;
  int q0 = qt * 256;
  size_t bhL = (size_t)bh * 1024;

  // stage hb rows: aligned 36-float window of QRH per q-row (start = (31-rx)&~3)
#pragma unroll
  for (int i = 0; i < 5; ++i) {
    int c = i * 512 + tid;  // 256 rows x 9 chunks = 2304
    if (c < 2304) {
      int row = c / 9, j = c % 9;
      int s0 = (31 - ((q0 + row) >> 5)) & ~3;
      *(uint4*)(hb_s + row * 40 + j * 4) =
          *(const uint4*)(QRH + (bhL + q0 + row) * 64 + s0 + j * 4);
    }
  }

  // per-q-set constants + direct global->reg loads (one-time)
  bf16x8 qa[2][4];
  float wb[2][2][4];
  int qloc[2], hbase[2];
#pragma unroll
  for (int u = 0; u < 2; ++u) {
    qloc[u] = wave * 32 + u * 16 + ln;
    int qg = q0 + qloc[u];
    int cx = qg & 31, rx = qg >> 5;
    hbase[u] = (31 - rx) & 3;
    const __hip_bfloat16* qrow = Qb + (bhL + qg) * 128;
#pragma unroll
    for (int ks = 0; ks < 4; ++ks)
      qa[u][ks] = *(const bf16x8*)(qrow + ks * 32 + g * 8);
    const float* wrow = QRW + (bhL + qg) * 64 + (31 - cx) + g * 4;
#pragma unroll
    for (int half = 0; half < 2; ++half)
#pragma unroll
      for (int r = 0; r < 4; ++r) wb[u][half][r] = wrow[half * 16 + r];
  }

  const char* Kg0 = (const char*)(Kb + bhL * 128);
  const char* Vg0 = (const char*)(Vt + (size_t)bh * 128 * 1024);
  int j3 = lane >> 3, j7 = lane & 7;
  int segv = ((j7 ^ j3) << 4);

  auto STAGE_K = [&](char* kvb, int kt2) {
    const char* Kg = Kg0 + (size_t)kt2 * 64 * 256;
#pragma unroll
    for (int i = 0; i < 2; ++i) {
      int R = (wave * 2 + i) * 4;  // chunk parity = i
      int seg = ((lane & 15) ^ ((i & 1) * 4 + (lane >> 4))) << 4;
      gload16(Kg + (size_t)(R + (lane >> 4)) * 256 + seg, kvb + R * 256);
    }
  };
  auto STAGE_V = [&](char* vtb, int kt2) {
    const char* Vg = Vg0 + (size_t)kt2 * 128;
#pragma unroll
    for (int i = 0; i < 2; ++i) {
      int R = (wave * 2 + i) * 8;
      gload16(Vg + (size_t)(R + j3) * 2048 + segv, vtb + R * 128);
    }
  };

  f32x4 acc[2][8] = {};
  float mrow[2] = {-1e30f, -1e30f}, lrow[2] = {0.f, 0.f};
  char* pw = pt + wave * 4096;

  // softmax(kp) on sO + P-write + PV from vprev
  auto SMPV = [&](int kp, f32x4 (&sO)[2][4], char* vprev) {
    float mt[2];
#pragma unroll
    for (int u = 0; u < 2; ++u) {
      float hb0 = hb_s[qloc[u] * 40 + hbase[u] + kp * 2];
      float hb1 = hb_s[qloc[u] * 40 + hbase[u] + kp * 2 + 1];
#pragma unroll
      for (int n = 0; n < 4; ++n) {
        float hb = (n >> 1) ? hb1 : hb0;
#pragma unroll
        for (int r = 0; r < 4; ++r) sO[u][n][r] += wb[u][n & 1][r] + hb;
      }
      float m = sO[u][0][0];
#pragma unroll
      for (int n = 0; n < 4; ++n)
#pragma unroll
        for (int r = 0; r < 4; ++r) m = fmaxf(m, sO[u][n][r]);
      m = fmaxf(m, __shfl_xor(m, 16, 64));
      mt[u] = fmaxf(m, __shfl_xor(m, 32, 64));
    }
    // T13 defer-rescale: only rescale when the running max grows by > 8
    bool grow = (mt[0] > mrow[0] + 8.f) || (mt[1] > mrow[1] + 8.f);
    if (__any(grow)) {
#pragma unroll
      for (int u = 0; u < 2; ++u) {
        float mn = fmaxf(mrow[u], mt[u]);
        float alpha = exp2f(mrow[u] - mn);
        mrow[u] = mn;
        lrow[u] *= alpha;
#pragma unroll
        for (int mf = 0; mf < 8; ++mf) acc[u][mf] *= alpha;
      }
    }
#pragma unroll
    for (int u = 0; u < 2; ++u) {
      float rs = 0.f;
#pragma unroll
      for (int n = 0; n < 4; ++n) {
#pragma unroll
        for (int r = 0; r < 4; ++r) {
          sO[u][n][r] = exp2f(sO[u][n][r] - mrow[u]);
          rs += sO[u][n][r];
        }
        ushort4 pk;
        pk.x = bits_bf16(sO[u][n][0]);
        pk.y = bits_bf16(sO[u][n][1]);
        pk.z = bits_bf16(sO[u][n][2]);
        pk.w = bits_bf16(sO[u][n][3]);
        *(ushort4*)(pw + (u * 16 + ln) * 128 + ((n * 32 + g * 8) ^ ((ln & 7) << 4))) = pk;
      }
      rs += __shfl_xor(rs, 16, 64);
      rs += __shfl_xor(rs, 32, 64);
      lrow[u] += rs;
    }
    // PV: acc[u][d][q] += V_t . P^T
    __builtin_amdgcn_s_setprio(1);
#pragma unroll
    for (int ks2 = 0; ks2 < 2; ++ks2) {
      int kcb = ks2 * 64 + (g << 4);
      bf16x8 pb0 = *(const bf16x8*)(pw + ln * 128 + (kcb ^ ((ln & 7) << 4)));
      bf16x8 pb1 = *(const bf16x8*)(pw + (16 + ln) * 128 + (kcb ^ ((ln & 7) << 4)));
#pragma unroll
      for (int mf = 0; mf < 8; ++mf) {
        int vrow = mf * 16 + ln;
        bf16x8 av = *(const bf16x8*)(vprev + vrow * 128 + (kcb ^ ((vrow & 7) << 4)));
        acc[0][mf] = __builtin_amdgcn_mfma_f32_16x16x32_bf16(av, pb0, acc[0][mf], 0, 0, 0);
        acc[1][mf] = __builtin_amdgcn_mfma_f32_16x16x32_bf16(av, pb1, acc[1][mf], 0, 0, 0);
      }
    }
    __builtin_amdgcn_s_setprio(0);
  };

  char *kc = kb0, *kn = kb1;
  char *vp = vb2, *vc = vb0, *vn = vb1;  // prev / cur / next (rotating)

  STAGE_K(kc, 0);
  STAGE_V(vc, 0);
  __syncthreads();  // tile 0 + hb_s ready

  f32x4 sA[2][4], sB[2][4];

  // one pipeline iteration: QK^T(kt)->sN, then softmax+PV(kt-1) on sO
  auto body = [&](int kt, f32x4 (&sN)[2][4], f32x4 (&sO)[2][4]) {
    if (kt < 15) {
      STAGE_K(kn, kt + 1);
      STAGE_V(vn, kt + 1);
    }
    // QK^T(kt) from kc (log2 domain): sN[u][n][r] = S[key=n*16+g*4+r][q=qloc[u]]
#pragma unroll
    for (int n = 0; n < 4; ++n) {
      sN[0][n] = (f32x4){0.f, 0.f, 0.f, 0.f};
      sN[1][n] = (f32x4){0.f, 0.f, 0.f, 0.f};
    }
    __builtin_amdgcn_s_setprio(1);
#pragma unroll
    for (int ks = 0; ks < 4; ++ks) {
      int kcol = ks * 64 + (g << 4);
#pragma unroll
      for (int n = 0; n < 4; ++n) {
        int krow = n * 16 + ln;
        bf16x8 kf = *(const bf16x8*)(kc + krow * 256 + (kcol ^ ((krow & 7) << 4)));
        sN[0][n] = __builtin_amdgcn_mfma_f32_16x16x32_bf16(kf, qa[0][ks], sN[0][n], 0, 0, 0);
        sN[1][n] = __builtin_amdgcn_mfma_f32_16x16x32_bf16(kf, qa[1][ks], sN[1][n], 0, 0, 0);
      }
    }
    __builtin_amdgcn_s_setprio(0);
    if (kt > 0) SMPV(kt - 1, sO, vp);
    __syncthreads();  // drains STAGE(kt+1); all waves done with kc/vp this epoch
    // rotate buffers
    char* t = kc; kc = kn; kn = t;
    char* t2 = vp; vp = vc; vc = vn; vn = t2;
  };

  for (int kt = 0; kt < 16; kt += 2) {
    body(kt, sA, sB);
    body(kt + 1, sB, sA);
  }
  // epilogue: softmax+PV for tile 15 (sB holds it; vp == V(15) after rotation)
  SMPV(15, sB, vp);

  // normalize + store (l and acc columns are in-lane per q-set)
#pragma unroll
  for (int u = 0; u < 2; ++u) {
    float linv = 1.0f / lrow[u];
    int qg3 = q0 + wave * 32 + u * 16 + ln;
#pragma unroll
    for (int mf = 0; mf < 8; ++mf) {
      int dbase = mf * 16 + g * 4;
#pragma unroll
      for (int r = 0; r < 4; ++r) {
        out[((size_t)(b * 512 + h * 128 + dbase + r)) * 1024 + qg3] = acc[u][mf][r] * linv;
      }
    }
  }
}

extern "C" void kernel_launch(void* const* d_in, const int* in_sizes, int n_in,
                              void* d_out, int out_size, void* d_ws, size_t ws_size,
                              hipStream_t stream) {
  const float* fm = (const float*)d_in[0];
  const float* wqk = (const float*)d_in[1];
  const float* wv = (const float*)d_in[2];
  const float* relh = (const float*)d_in[3];
  const float* relw = (const float*)d_in[4];
  float* out = (float*)d_out;
  char* w = (char*)d_ws;

  __hip_bfloat16* fmt = (__hip_bfloat16*)w;                   // 16 MB  [B][L][C]
  __hip_bfloat16* wall = (__hip_bfloat16*)(w + 16777216);     // 1.5 MB [1536][512]
  __hip_bfloat16* Qb = (__hip_bfloat16*)(w + 18350080);       // 16 MB  [B][H][L][D] (scaled*log2e)
  __hip_bfloat16* Kb = (__hip_bfloat16*)(w + 35127296);       // 16 MB  [B][H][L][D]
  __hip_bfloat16* Vt = (__hip_bfloat16*)(w + 51904512);       // 16 MB  [B][H][D][L]
  float* QRW = (float*)(w + 68681728);                        // 16 MB  [B][H][L][64]
  float* QRH = (float*)(w + 85458944);                        // 16 MB  [B][H][L][64]
  __hip_bfloat16* relsb = (__hip_bfloat16*)(w + 102236160);   // 32 KB  [2][64][128]

  hipFuncSetAttribute((const void*)k_attn,
                      hipFuncAttributeMaxDynamicSharedMemorySize, 155648);

  k_convw<<<3136, 256, 0, stream>>>(wqk, wv, relw, relh, wall, relsb);
  k_tfm<<<dim3(16, 8, 16), 256, 0, stream>>>(fm, fmt);
  k_gemm<<<dim3(8, 12, 16), 256, 0, stream>>>(fmt, wall, Qb, Kb, Vt);
  k_bias<<<dim3(8, 64), 256, 0, stream>>>(Qb, relsb, QRW, QRH);
  k_attn<<<dim3(64, 4), 512, 155648, stream>>>(Qb, Kb, Vt, QRW, QRH, out);
}